// Round 4
// baseline (658.975 us; speedup 1.0000x reference)
//
#include <hip/hip_runtime.h>
#include <hip/hip_bf16.h>
#include <cstdint>
#include <cstddef>

#define B_     4
#define T_     256
#define S_     256
#define D_     512
#define V_     32000
#define H_     8
#define DH_    64
#define HID_   512
#define VEXT_  32512
#define BT_    1024   // B*T == B*S
#define CHUNK_ 8192   // floats of LDS per epilogue chunk (32 KB)

typedef __hip_bfloat16 bf16;
typedef __bf16 bf16x8 __attribute__((ext_vector_type(8)));
typedef float  f32x4  __attribute__((ext_vector_type(4)));

// ---------- helpers ----------
__device__ inline void store_val(float* p, float v) { *p = v; }
__device__ inline void store_val(bf16* p, float v)  { *p = __float2bfloat16(v); }

__device__ inline float bfbits2f(unsigned short u) {
    return __uint_as_float(((unsigned)u) << 16);
}
__device__ inline unsigned short f2bfbits(float f) {
    bf16 h = __float2bfloat16(f);
    union { bf16 h; unsigned short u; } cv; cv.h = h; return cv.u;
}

// ---------- dtype probe: flag=1 if input looks like fp32, 0 if bf16 ----------
// bf16 N(0,1) data: nearly all uint16s have exp field in [96,159].
// fp32 N(0,1) data: high halves yes (~50%), low halves uniform (~25% hit) -> ~62%.
__global__ void probe_kernel(const unsigned short* __restrict__ x, int* __restrict__ flag)
{
    __shared__ int cnt;
    if (threadIdx.x == 0) cnt = 0;
    __syncthreads();
    int c = 0;
    for (int i = threadIdx.x; i < 4096; i += 256) {
        const int e = (x[i] >> 7) & 0xFF;
        if (e >= 96 && e <= 159) c++;
    }
    atomicAdd(&cnt, c);
    __syncthreads();
    if (threadIdx.x == 0) *flag = (cnt < 3500) ? 1 : 0;
}

// ---------- convert input -> bf16 copy (fp32 narrows, bf16 raw-copies) ----------
__global__ void convert_kernel(const void* __restrict__ src, bf16* __restrict__ dst,
                               int n, const int* __restrict__ flag)
{
    const int stride = gridDim.x * 256;
    const int i0 = blockIdx.x * 256 + threadIdx.x;
    if (*flag) {
        const float* s = (const float*)src;
        for (int i = i0; i < n; i += stride) dst[i] = __float2bfloat16(s[i]);
    } else {
        const unsigned short* s = (const unsigned short*)src;
        unsigned short* d = (unsigned short*)dst;
        for (int i = i0; i < n; i += stride) d[i] = s[i];
    }
}

// ---------- masks: sign(sum|x|) over D for tgt/src1/src2 ----------
__global__ void masks_kernel(const bf16* __restrict__ tgt, const bf16* __restrict__ s1,
                             const bf16* __restrict__ s2, float* __restrict__ mt,
                             float* __restrict__ m1, float* __restrict__ m2)
{
    const int row = blockIdx.x;
    const bf16* src; float* dst;
    if (row < BT_)           { src = tgt + (size_t)row * D_;            dst = mt + row; }
    else if (row < 2 * BT_)  { src = s1 + (size_t)(row - BT_) * D_;     dst = m1 + (row - BT_); }
    else                     { src = s2 + (size_t)(row - 2 * BT_) * D_; dst = m2 + (row - 2 * BT_); }
    const int lane = threadIdx.x;
    float s = 0.f;
    for (int i = lane; i < D_; i += 64) s += fabsf(__bfloat162float(src[i]));
#pragma unroll
    for (int off = 32; off; off >>= 1) s += __shfl_down(s, off);
    if (lane == 0) *dst = (s > 0.f) ? 1.f : 0.f;
}

// ---------- MFMA GEMM: C[m,n] = sum_k A[m,k]*B[n,k] + bias[n] ----------
template <typename OutT>
__global__ __launch_bounds__(256)
void gemm_bt_kernel(const bf16* __restrict__ A, const bf16* __restrict__ Bw,
                    const bf16* __restrict__ bias, OutT* __restrict__ C,
                    int N, int K, int ldC)
{
    __shared__ bf16 As[128 * 32];
    __shared__ bf16 Bs[128 * 32];
    const int tid  = threadIdx.x;
    const int lane = tid & 63;
    const int wave = tid >> 6;
    const int quad = lane >> 4, l16 = lane & 15;
    const int m0 = blockIdx.y * 128, n0 = blockIdx.x * 128;
    const int wm = (wave >> 1) * 64, wn = (wave & 1) * 64;

    f32x4 acc[4][4];
#pragma unroll
    for (int i = 0; i < 4; i++)
#pragma unroll
        for (int j = 0; j < 4; j++) acc[i][j] = (f32x4){0.f, 0.f, 0.f, 0.f};

    const int row0 = tid >> 2;        // 0..63
    const int kp   = (tid & 3) * 8;   // 0,8,16,24 (elements)

    for (int k0 = 0; k0 < K; k0 += 32) {
        uint4 a0 = *(const uint4*)(A  + (size_t)(m0 + row0)      * K + k0 + kp);
        uint4 a1 = *(const uint4*)(A  + (size_t)(m0 + row0 + 64) * K + k0 + kp);
        uint4 b0 = *(const uint4*)(Bw + (size_t)(n0 + row0)      * K + k0 + kp);
        uint4 b1 = *(const uint4*)(Bw + (size_t)(n0 + row0 + 64) * K + k0 + kp);
        __syncthreads();
        *(uint4*)(As + row0 * 32 + kp)        = a0;
        *(uint4*)(As + (row0 + 64) * 32 + kp) = a1;
        *(uint4*)(Bs + row0 * 32 + kp)        = b0;
        *(uint4*)(Bs + (row0 + 64) * 32 + kp) = b1;
        __syncthreads();

        bf16x8 af[4], bfv[4];
#pragma unroll
        for (int i = 0; i < 4; i++)
            af[i] = *(const bf16x8*)(As + (wm + i * 16 + l16) * 32 + quad * 8);
#pragma unroll
        for (int j = 0; j < 4; j++)
            bfv[j] = *(const bf16x8*)(Bs + (wn + j * 16 + l16) * 32 + quad * 8);
#pragma unroll
        for (int i = 0; i < 4; i++)
#pragma unroll
            for (int j = 0; j < 4; j++)
                acc[i][j] = __builtin_amdgcn_mfma_f32_16x16x32_bf16(af[i], bfv[j], acc[i][j], 0, 0, 0);
    }

#pragma unroll
    for (int i = 0; i < 4; i++)
#pragma unroll
        for (int j = 0; j < 4; j++) {
            const int nb = n0 + wn + j * 16 + l16;
            const float bv = __bfloat162float(bias[nb]);
#pragma unroll
            for (int r = 0; r < 4; r++) {
                const int m = m0 + wm + i * 16 + quad * 4 + r;
                store_val(C + (size_t)m * ldC + nb, acc[i][j][r] + bv);
            }
        }
}

// ---------- fc GEMM variant: writes into out at out's native dtype (flag) ----------
__global__ __launch_bounds__(256)
void gemm_fc_kernel(const bf16* __restrict__ A, const bf16* __restrict__ Bw,
                    const bf16* __restrict__ bias, void* __restrict__ Cv,
                    const int* __restrict__ flag, int N, int K, int ldC)
{
    __shared__ bf16 As[128 * 32];
    __shared__ bf16 Bs[128 * 32];
    const int fm = *flag;
    const int tid  = threadIdx.x;
    const int lane = tid & 63;
    const int wave = tid >> 6;
    const int quad = lane >> 4, l16 = lane & 15;
    const int m0 = blockIdx.y * 128, n0 = blockIdx.x * 128;
    const int wm = (wave >> 1) * 64, wn = (wave & 1) * 64;

    f32x4 acc[4][4];
#pragma unroll
    for (int i = 0; i < 4; i++)
#pragma unroll
        for (int j = 0; j < 4; j++) acc[i][j] = (f32x4){0.f, 0.f, 0.f, 0.f};

    const int row0 = tid >> 2;
    const int kp   = (tid & 3) * 8;

    for (int k0 = 0; k0 < K; k0 += 32) {
        uint4 a0 = *(const uint4*)(A  + (size_t)(m0 + row0)      * K + k0 + kp);
        uint4 a1 = *(const uint4*)(A  + (size_t)(m0 + row0 + 64) * K + k0 + kp);
        uint4 b0 = *(const uint4*)(Bw + (size_t)(n0 + row0)      * K + k0 + kp);
        uint4 b1 = *(const uint4*)(Bw + (size_t)(n0 + row0 + 64) * K + k0 + kp);
        __syncthreads();
        *(uint4*)(As + row0 * 32 + kp)        = a0;
        *(uint4*)(As + (row0 + 64) * 32 + kp) = a1;
        *(uint4*)(Bs + row0 * 32 + kp)        = b0;
        *(uint4*)(Bs + (row0 + 64) * 32 + kp) = b1;
        __syncthreads();

        bf16x8 af[4], bfv[4];
#pragma unroll
        for (int i = 0; i < 4; i++)
            af[i] = *(const bf16x8*)(As + (wm + i * 16 + l16) * 32 + quad * 8);
#pragma unroll
        for (int j = 0; j < 4; j++)
            bfv[j] = *(const bf16x8*)(Bs + (wn + j * 16 + l16) * 32 + quad * 8);
#pragma unroll
        for (int i = 0; i < 4; i++)
#pragma unroll
            for (int j = 0; j < 4; j++)
                acc[i][j] = __builtin_amdgcn_mfma_f32_16x16x32_bf16(af[i], bfv[j], acc[i][j], 0, 0, 0);
    }

#pragma unroll
    for (int i = 0; i < 4; i++)
#pragma unroll
        for (int j = 0; j < 4; j++) {
            const int nb = n0 + wn + j * 16 + l16;
            const float bv = __bfloat162float(bias[nb]);
#pragma unroll
            for (int r = 0; r < 4; r++) {
                const int m = m0 + wm + i * 16 + quad * 4 + r;
                const float val = acc[i][j][r] + bv;
                if (fm) ((float*)Cv)[(size_t)m * ldC + nb] = val;
                else    ((bf16*)Cv)[(size_t)m * ldC + nb] = __float2bfloat16(val);
            }
        }
}

// ---------- fused attention: per (b,t) block, all heads ----------
__global__ __launch_bounds__(256)
void fused_attn_kernel(const bf16* __restrict__ q, const bf16* __restrict__ k,
                       const bf16* __restrict__ v, const float* __restrict__ qmask,
                       const float* __restrict__ kmask, bf16* __restrict__ ctx,
                       float* __restrict__ lnout)
{
    __shared__ float qs[HID_];
    __shared__ float pvs[S_];
    __shared__ float part[4][DH_];
    __shared__ float red[4];
    const int bt = blockIdx.x, b = bt >> 8, tid = threadIdx.x;
    const int lane = tid & 63, wv = tid >> 6;

    for (int d = tid; d < HID_; d += 256)
        qs[d] = __bfloat162float(q[(size_t)bt * HID_ + d]) * 0.125f;
    const float km = kmask[b * S_ + tid];
    const bool on = km != 0.f;
    __syncthreads();

    float msum = 0.f;
    for (int h = 0; h < H_; h++) {
        const bf16* kp = k + (size_t)(b * S_ + tid) * HID_ + h * DH_;
        const float* qh = qs + h * DH_;
        float sc = 0.f;
#pragma unroll
        for (int d = 0; d < DH_; d += 8) {
            ushort4 u0 = *(const ushort4*)(kp + d);
            ushort4 u1 = *(const ushort4*)(kp + d + 4);
            sc += qh[d + 0] * bfbits2f(u0.x) + qh[d + 1] * bfbits2f(u0.y)
                + qh[d + 2] * bfbits2f(u0.z) + qh[d + 3] * bfbits2f(u0.w)
                + qh[d + 4] * bfbits2f(u1.x) + qh[d + 5] * bfbits2f(u1.y)
                + qh[d + 6] * bfbits2f(u1.z) + qh[d + 7] * bfbits2f(u1.w);
        }
        msum += sc;

        float x = on ? sc : -INFINITY;
        float m = x;
#pragma unroll
        for (int off = 32; off; off >>= 1) m = fmaxf(m, __shfl_down(m, off));
        __syncthreads();
        if (lane == 0) red[wv] = m;
        __syncthreads();
        const float mx = fmaxf(fmaxf(red[0], red[1]), fmaxf(red[2], red[3]));
        float e = (on && mx > -INFINITY) ? __expf(x - mx) : 0.f;
        float ts = e;
#pragma unroll
        for (int off = 32; off; off >>= 1) ts += __shfl_down(ts, off);
        __syncthreads();
        if (lane == 0) red[wv] = ts;
        __syncthreads();
        const float ssum = red[0] + red[1] + red[2] + red[3];
        const float inv = (ssum > 0.f) ? 1.f / ssum : 0.f;
        pvs[tid] = e * inv;
        __syncthreads();

        const bf16* vp = v + (size_t)(b * S_ + wv * 64) * HID_ + h * DH_ + lane;
        float a = 0.f;
#pragma unroll 4
        for (int s = 0; s < 64; s++)
            a += pvs[wv * 64 + s] * __bfloat162float(vp[(size_t)s * HID_]);
        part[wv][lane] = a;
        __syncthreads();
        if (tid < 64) {
            float o = part[0][tid] + part[1][tid] + part[2][tid] + part[3][tid];
            ctx[(size_t)bt * HID_ + h * DH_ + tid] = __float2bfloat16(o);
        }
    }

    const float qm = qmask[bt];
    const float am = msum * (1.f / H_) * km * qm;
    float t1 = am;
#pragma unroll
    for (int off = 32; off; off >>= 1) t1 += __shfl_down(t1, off);
    __syncthreads();
    if (lane == 0) red[wv] = t1;
    __syncthreads();
    const float mean = (red[0] + red[1] + red[2] + red[3]) * (1.f / S_);
    float dv = (am - mean) * (am - mean);
#pragma unroll
    for (int off = 32; off; off >>= 1) dv += __shfl_down(dv, off);
    __syncthreads();
    if (lane == 0) red[wv] = dv;
    __syncthreads();
    const float rstd = rsqrtf(fmaxf((red[0] + red[1] + red[2] + red[3]) * (1.f / S_), 0.f) + 1e-5f);
    lnout[(size_t)bt * S_ + tid] = (am - mean) * rstd;
}

// ---------- gate ----------
__global__ void pgate_kernel(const bf16* __restrict__ x, const float* __restrict__ c1,
                             const float* __restrict__ c2, const float* __restrict__ qmask,
                             const bf16* __restrict__ Wp, const bf16* __restrict__ bp,
                             float* __restrict__ p)
{
    const int bt = blockIdx.x;
    const int lane = threadIdx.x;   // 64
    const float qm = qmask[bt];
    float a0 = 0.f, a1 = 0.f, a2 = 0.f;
    for (int d = lane; d < D_; d += 64) {
        const float xv  = __bfloat162float(x[(size_t)bt * D_ + d]);
        const float c1v = c1[(size_t)bt * D_ + d] * qm;
        const float c2v = c2[(size_t)bt * D_ + d] * qm;
        a0 += xv * __bfloat162float(Wp[0 * 3 * D_ + d])
            + c1v * __bfloat162float(Wp[0 * 3 * D_ + D_ + d])
            + c2v * __bfloat162float(Wp[0 * 3 * D_ + 2 * D_ + d]);
        a1 += xv * __bfloat162float(Wp[1 * 3 * D_ + d])
            + c1v * __bfloat162float(Wp[1 * 3 * D_ + D_ + d])
            + c2v * __bfloat162float(Wp[1 * 3 * D_ + 2 * D_ + d]);
        a2 += xv * __bfloat162float(Wp[2 * 3 * D_ + d])
            + c1v * __bfloat162float(Wp[2 * 3 * D_ + D_ + d])
            + c2v * __bfloat162float(Wp[2 * 3 * D_ + 2 * D_ + d]);
    }
#pragma unroll
    for (int off = 32; off; off >>= 1) {
        a0 += __shfl_down(a0, off);
        a1 += __shfl_down(a1, off);
        a2 += __shfl_down(a2, off);
    }
    if (lane == 0) {
        float l0 = a0 + __bfloat162float(bp[0]);
        float l1 = a1 + __bfloat162float(bp[1]);
        float l2 = a2 + __bfloat162float(bp[2]);
        float mx = fmaxf(l0, fmaxf(l1, l2));
        float e0 = __expf(l0 - mx), e1 = __expf(l1 - mx), e2 = __expf(l2 - mx);
        float inv = 1.f / (e0 + e1 + e2);
        p[bt * 3 + 0] = e0 * inv; p[bt * 3 + 1] = e1 * inv; p[bt * 3 + 2] = e2 * inv;
    }
}

// ---------- fc row stats over V; fc lives in out rows at native dtype ----------
__global__ __launch_bounds__(256)
void fcstats_kernel(const void* __restrict__ outv, const int* __restrict__ flag,
                    float* __restrict__ stats)
{
    const int fm = *flag;
    const int bt = blockIdx.x;
    const size_t rbase = (size_t)bt * VEXT_;
    float s = 0.f, s2 = 0.f;
    if (fm) {
        const float* rp = (const float*)outv + rbase;
        for (int j = threadIdx.x * 4; j < V_; j += 1024) {
            float4 v = *(const float4*)(rp + j);
            s  += v.x + v.y + v.z + v.w;
            s2 += v.x * v.x + v.y * v.y + v.z * v.z + v.w * v.w;
        }
    } else {
        const unsigned short* rp = (const unsigned short*)outv + rbase;
        for (int j = threadIdx.x * 4; j < V_; j += 1024) {
            ushort4 u = *(const ushort4*)(rp + j);
            float v0 = bfbits2f(u.x), v1 = bfbits2f(u.y), v2 = bfbits2f(u.z), v3 = bfbits2f(u.w);
            s  += v0 + v1 + v2 + v3;
            s2 += v0 * v0 + v1 * v1 + v2 * v2 + v3 * v3;
        }
    }
    const int lane = threadIdx.x & 63, wv = threadIdx.x >> 6;
#pragma unroll
    for (int off = 32; off; off >>= 1) { s += __shfl_down(s, off); s2 += __shfl_down(s2, off); }
    __shared__ float rs[4], rq[4];
    if (lane == 0) { rs[wv] = s; rq[wv] = s2; }
    __syncthreads();
    if (threadIdx.x == 0) {
        float S = rs[0] + rs[1] + rs[2] + rs[3];
        float Q = rq[0] + rq[1] + rq[2] + rq[3];
        float mean = S * (1.f / V_);
        float var = fmaxf(Q * (1.f / V_) - mean * mean, 0.f);
        stats[bt * 2] = mean;
        stats[bt * 2 + 1] = rsqrtf(var + 1e-5f);
    }
}

// ---------- in-place epilogue on out: LN(fc)*p0, scatter, store native dtype ----------
__global__ __launch_bounds__(256)
void final_kernel(void* __restrict__ outv, const int* __restrict__ flag,
                  const float* __restrict__ ln1, const float* __restrict__ ln2,
                  const int* __restrict__ map1, const int* __restrict__ map2,
                  const float* __restrict__ p, const float* __restrict__ stats)
{
    __shared__ float chnk[CHUNK_];
    const int fm = *flag;
    const int bt = blockIdx.x, b = bt >> 8, tid = threadIdx.x;
    const float p0 = p[bt * 3], p1 = p[bt * 3 + 1], p2 = p[bt * 3 + 2];
    const float m = stats[bt * 2], r = stats[bt * 2 + 1];
    const size_t rbase = (size_t)bt * VEXT_;

    for (int c = 0; c < 4; c++) {
        const int jlo = c * CHUNK_;
        const int n = (VEXT_ - jlo < CHUNK_) ? (VEXT_ - jlo) : CHUNK_;
        // load + normalize + gate (pad -> 0)
        for (int jj = tid * 4; jj < n; jj += 1024) {
            const int j = jlo + jj;
            float4 fv = {0.f, 0.f, 0.f, 0.f};
            if (j < V_) {
                float v0, v1, v2, v3;
                if (fm) {
                    float4 u = *(const float4*)((const float*)outv + rbase + j);
                    v0 = u.x; v1 = u.y; v2 = u.z; v3 = u.w;
                } else {
                    ushort4 u = *(const ushort4*)((const unsigned short*)outv + rbase + j);
                    v0 = bfbits2f(u.x); v1 = bfbits2f(u.y); v2 = bfbits2f(u.z); v3 = bfbits2f(u.w);
                }
                fv.x = p0 * (v0 - m) * r;
                fv.y = p0 * (v1 - m) * r;
                fv.z = p0 * (v2 - m) * r;
                fv.w = p0 * (v3 - m) * r;
            }
            *(float4*)(chnk + jj) = fv;
        }
        __syncthreads();
        // scatter contributions landing in this chunk
        for (int e = tid; e < 2 * S_; e += 256) {
            const int src = e >> 8, si = e & 255;
            const int j = (src ? map2 : map1)[b * S_ + si];
            if (j >= jlo && j < jlo + n) {
                const float val = (src ? p2 : p1) * (src ? ln2 : ln1)[(size_t)bt * S_ + si];
                atomicAdd(&chnk[j - jlo], val);
            }
        }
        __syncthreads();
        // store back native dtype
        if (fm) {
            float* orow = (float*)outv + rbase;
            for (int jj = tid * 4; jj < n; jj += 1024)
                *(float4*)(orow + jlo + jj) = *(const float4*)(chnk + jj);
        } else {
            unsigned short* orow = (unsigned short*)outv + rbase;
            for (int jj = tid * 4; jj < n; jj += 1024) {
                float4 v = *(const float4*)(chnk + jj);
                ushort4 u;
                u.x = f2bfbits(v.x); u.y = f2bfbits(v.y); u.z = f2bfbits(v.z); u.w = f2bfbits(v.w);
                *(ushort4*)(orow + jlo + jj) = u;
            }
        }
        __syncthreads();
    }
}

// ---------- launch ----------
extern "C" void kernel_launch(void* const* d_in, const int* in_sizes, int n_in,
                              void* d_out, int out_size, void* d_ws, size_t ws_size,
                              hipStream_t stream)
{
    const int* map1 = (const int*)d_in[2];
    const int* map2 = (const int*)d_in[4];

    char* w = (char*)d_ws;
    size_t off = 0;
    auto carve = [&](size_t bytes) -> char* {
        char* ptr = w + off;
        off = (off + bytes + 255) & ~(size_t)255;
        return ptr;
    };
    int* flag = (int*)carve(16);

    // converted bf16 copies of all float inputs
    bf16* xc   = (bf16*)carve((size_t)BT_ * D_ * 2);
    bf16* s1c  = (bf16*)carve((size_t)B_ * S_ * D_ * 2);
    bf16* s2c  = (bf16*)carve((size_t)B_ * S_ * D_ * 2);
    bf16* Wfcc = (bf16*)carve((size_t)V_ * D_ * 2);
    bf16* bfcc = (bf16*)carve((size_t)V_ * 2);
    bf16* Wpc  = (bf16*)carve((size_t)3 * 3 * D_ * 2);
    bf16* bpc  = (bf16*)carve(3 * 2);
    bf16* Wc[8]; bf16* bc[8];
    for (int i = 0; i < 8; i++) {
        Wc[i] = (bf16*)carve((size_t)HID_ * D_ * 2);
        bc[i] = (bf16*)carve((size_t)HID_ * 2);
    }

    // pipeline scratch
    bf16*  q1    = (bf16*) carve((size_t)BT_ * HID_ * 2);
    bf16*  k1    = (bf16*) carve((size_t)BT_ * HID_ * 2);
    bf16*  v1    = (bf16*) carve((size_t)BT_ * HID_ * 2);
    bf16*  q2    = (bf16*) carve((size_t)BT_ * HID_ * 2);
    bf16*  k2    = (bf16*) carve((size_t)BT_ * HID_ * 2);
    bf16*  v2    = (bf16*) carve((size_t)BT_ * HID_ * 2);
    bf16*  ctx1  = (bf16*) carve((size_t)BT_ * HID_ * 2);
    bf16*  ctx2  = (bf16*) carve((size_t)BT_ * HID_ * 2);
    float* c1    = (float*)carve((size_t)BT_ * HID_ * 4);
    float* c2    = (float*)carve((size_t)BT_ * HID_ * 4);
    float* ln1   = (float*)carve((size_t)BT_ * S_ * 4);
    float* ln2   = (float*)carve((size_t)BT_ * S_ * 4);
    float* p     = (float*)carve((size_t)BT_ * 3 * 4);
    float* mt    = (float*)carve((size_t)BT_ * 4);
    float* m1    = (float*)carve((size_t)BT_ * 4);
    float* m2    = (float*)carve((size_t)BT_ * 4);
    float* stats = (float*)carve((size_t)BT_ * 2 * 4);
    (void)ws_size; (void)in_sizes; (void)n_in; (void)out_size;  // total ~53 MB

    // 1. dtype probe
    probe_kernel<<<1, 256, 0, stream>>>((const unsigned short*)d_in[0], flag);

    // 2. convert all float inputs to bf16 copies
    auto conv = [&](const void* src, bf16* dst, int n) {
        int blocks = (n + 255) / 256;
        if (blocks > 4096) blocks = 4096;
        convert_kernel<<<blocks, 256, 0, stream>>>(src, dst, n, flag);
    };
    conv(d_in[0], xc,   BT_ * D_);
    conv(d_in[1], s1c,  B_ * S_ * D_);
    conv(d_in[3], s2c,  B_ * S_ * D_);
    conv(d_in[5], Wfcc, V_ * D_);
    conv(d_in[6], bfcc, V_);
    conv(d_in[7], Wpc,  3 * 3 * D_);
    conv(d_in[8], bpc,  3);
    for (int i = 0; i < 8; i++) {
        conv(d_in[9 + 2 * i],  Wc[i], HID_ * D_);
        conv(d_in[10 + 2 * i], bc[i], HID_);
    }

    // 3. masks
    masks_kernel<<<3 * BT_, 64, 0, stream>>>(xc, s1c, s2c, mt, m1, m2);

    // 4. big fc gemm -> out rows (native dtype, stride VEXT)
    dim3 gfc(V_ / 128, BT_ / 128);
    gemm_fc_kernel<<<gfc, 256, 0, stream>>>(xc, Wfcc, bfcc, d_out, flag, V_, D_, VEXT_);

    // 5. projections (bf16)
    dim3 gproj(HID_ / 128, BT_ / 128);
    gemm_bt_kernel<bf16><<<gproj, 256, 0, stream>>>(xc,  Wc[0], bc[0], q1, HID_, D_, HID_);
    gemm_bt_kernel<bf16><<<gproj, 256, 0, stream>>>(s1c, Wc[1], bc[1], k1, HID_, D_, HID_);
    gemm_bt_kernel<bf16><<<gproj, 256, 0, stream>>>(s1c, Wc[2], bc[2], v1, HID_, D_, HID_);
    gemm_bt_kernel<bf16><<<gproj, 256, 0, stream>>>(xc,  Wc[4], bc[4], q2, HID_, D_, HID_);
    gemm_bt_kernel<bf16><<<gproj, 256, 0, stream>>>(s2c, Wc[5], bc[5], k2, HID_, D_, HID_);
    gemm_bt_kernel<bf16><<<gproj, 256, 0, stream>>>(s2c, Wc[6], bc[6], v2, HID_, D_, HID_);

    // 6. fused attention
    fused_attn_kernel<<<BT_, 256, 0, stream>>>(q1, k1, v1, mt, m1, ctx1, ln1);
    fused_attn_kernel<<<BT_, 256, 0, stream>>>(q2, k2, v2, mt, m2, ctx2, ln2);

    // 7. out-projections (fp32 out)
    gemm_bt_kernel<float><<<gproj, 256, 0, stream>>>(ctx1, Wc[3], bc[3], c1, HID_, D_, HID_);
    gemm_bt_kernel<float><<<gproj, 256, 0, stream>>>(ctx2, Wc[7], bc[7], c2, HID_, D_, HID_);

    // 8. gate
    pgate_kernel<<<BT_, 64, 0, stream>>>(xc, c1, c2, mt, Wpc, bpc, p);

    // 9. fc stats then fused in-place epilogue on out
    fcstats_kernel<<<BT_, 256, 0, stream>>>(d_out, flag, stats);
    final_kernel<<<BT_, 256, 0, stream>>>(d_out, flag, ln1, ln2, map1, map2, p, stats);
}